// Round 15
// baseline (202.891 us; speedup 1.0000x reference)
//
#include <hip/hip_runtime.h>
#include <hip/hip_bf16.h>

#define DMODEL 1024
#define NHEAD  16
#define DKD    64
#define BLK    128
#define TB     16
#define SCALEF 0.125f   // TAU / sqrt(DK)

typedef __attribute__((ext_vector_type(8))) short bf16x8;
typedef __attribute__((ext_vector_type(4))) _Float16 f16x4;
typedef __attribute__((ext_vector_type(4))) float f32x4;
typedef __attribute__((ext_vector_type(4))) unsigned int ui4;

#define MFMA(A, B, C)   __builtin_amdgcn_mfma_f32_16x16x32_bf16(A, B, C, 0, 0, 0)
#define MFMA16(A, B, C) __builtin_amdgcn_mfma_f32_16x16x16f16(A, B, C, 0, 0, 0)

union U8 { bf16x8 v; ushort u[8]; ushort2 u2[4]; ushort4 u4[2]; };

__device__ __forceinline__ ushort2 pk2(float a, float b) {
  union { __hip_bfloat162 h; ushort2 u; } c;
  c.h = __float22bfloat162_rn(make_float2(a, b));
  return c.u;
}
__device__ __forceinline__ ushort4 pkh4(float a, float b, float c, float d) {
  union { f16x4 h; ushort4 u; } z;
  z.h[0] = (_Float16)a; z.h[1] = (_Float16)b;
  z.h[2] = (_Float16)c; z.h[3] = (_Float16)d;
  return z.u;
}

// ---- tile-image readers ---------------------------------------------------
// row tile [128][64] bf16, XOR-swizzled by ((r&7)<<3)   (R2-proven)
__device__ __forceinline__ bf16x8 frag64(const ushort* T, int r, int c) {
  return *reinterpret_cast<const bf16x8*>(T + ((r * 64 + c) ^ ((r & 7) << 3)));
}
// [128][128] bf16 tile, same swizzle  (R2-proven)
__device__ __forceinline__ bf16x8 frag128(const ushort* T, int r, int c) {
  return *reinterpret_cast<const bf16x8*>(T + ((r * 128 + c) ^ ((r & 7) << 3)));
}
// depth-8 chunked transposed tile [64 d][128 r]: elem (d,r) at
// (r>>3)*512 + d*8 + (r&7)  (R13-proven correct)
__device__ __forceinline__ bf16x8 fragT8(const ushort* T, int d, int r0) {
  return *reinterpret_cast<const bf16x8*>(T + (r0 >> 3) * 512 + d * 8);  // r0%8==0
}
// K=16 A-frag from fp16 depth-8 tile: elems (d, 4g..4g+3) -> one b64 read
__device__ __forceinline__ f16x4 fragK16(const ushort* T, int d, int g) {
  union { ushort4 u; f16x4 h; } z;
  z.u = *reinterpret_cast<const ushort4*>(T + (g >> 1) * 512 + d * 8 + 4 * (g & 1));
  return z.h;
}
// global fp32 row-major -> bf16 register fragment
__device__ __forceinline__ bf16x8 gfrag(const float* __restrict__ g, float sc) {
  const float4 fa = *reinterpret_cast<const float4*>(g);
  const float4 fb = *reinterpret_cast<const float4*>(g + 4);
  U8 x;
  x.u2[0] = pk2(fa.x * sc, fa.y * sc);
  x.u2[1] = pk2(fa.z * sc, fa.w * sc);
  x.u2[2] = pk2(fb.x * sc, fb.y * sc);
  x.u2[3] = pk2(fb.z * sc, fb.w * sc);
  return x.v;
}

// ---- prepass image writers (512 threads) ----------------------------------
__device__ __forceinline__ void gwrow(ushort* T, const float* __restrict__ g,
                                      float sc, int tid) {
#pragma unroll
  for (int it = 0; it < 4; ++it) {
    const int idx = tid + 512 * it;
    const int r = idx >> 4, d4 = idx & 15;
    const float4 f = *reinterpret_cast<const float4*>(g + r * DMODEL + 4 * d4);
    const ushort2 lo = pk2(f.x * sc, f.y * sc);
    const ushort2 hi = pk2(f.z * sc, f.w * sc);
    ushort4 u; u.x = lo.x; u.y = lo.y; u.z = hi.x; u.w = hi.y;
    *reinterpret_cast<ushort4*>(T + ((r * 64 + 4 * d4) ^ ((r & 7) << 3))) = u;
  }
}
// shfl butterfly transpose -> depth-8 chunked tile; HALF=1 => fp16 payload
template <int HALF>
__device__ __forceinline__ void gwchunk(ushort* T, const float* __restrict__ g,
                                        float sc, int tid) {
  const int a = (tid >> 4) & 3;
#pragma unroll
  for (int it = 0; it < 4; ++it) {
    const int idx = tid + 512 * it;
    const int r = idx >> 4, d4 = idx & 15;
    const float4 f = *reinterpret_cast<const float4*>(g + r * DMODEL + 4 * d4);
    const float w0 = f.x * sc, w1 = f.y * sc, w2 = f.z * sc, w3 = f.w * sc;
    const float s0 = __shfl_xor(w1, 16), s1 = __shfl_xor(w0, 16);
    const float s2 = __shfl_xor(w3, 16), s3 = __shfl_xor(w2, 16);
    const float u0 = (a & 1) ? s0 : w0;
    const float u1 = (a & 1) ? w1 : s1;
    const float u2 = (a & 1) ? s2 : w2;
    const float u3 = (a & 1) ? w3 : s3;
    const float t0 = __shfl_xor(u2, 32), t1 = __shfl_xor(u3, 32);
    const float t2 = __shfl_xor(u0, 32), t3 = __shfl_xor(u1, 32);
    const float z0 = (a & 2) ? t0 : u0;
    const float z1 = (a & 2) ? t1 : u1;
    const float z2 = (a & 2) ? u2 : t2;
    const float z3 = (a & 2) ? u3 : t3;
    const int d = 4 * d4 + a, R0 = r - a;   // lane holds rows R0..R0+3 of col d
    ushort4 o;
    if constexpr (HALF) {
      o = pkh4(z0, z1, z2, z3);
    } else {
      const ushort2 lo = pk2(z0, z1);
      const ushort2 hi = pk2(z2, z3);
      o.x = lo.x; o.y = lo.y; o.z = hi.x; o.w = hi.y;
    }
    *reinterpret_cast<ushort4*>(T + (R0 >> 3) * 512 + d * 8 + (R0 & 7)) = o;
  }
}

// images per (h,t): 0 KR(bf16,k*s) 1 VR(bf16,v) 2 KT16(fp16,k*s,d8)
//                   3 QT(bf16,q*s,d8) 4 OT(bf16,dO,d8) 5 QR(bf16,q) 6 OR(bf16,dO)
__device__ __forceinline__ ushort* IMGp(ushort* ws, int imgN, int h, int t, int i) {
  return ws + (((size_t)h * TB + t) * imgN + i) * 8192;
}
__device__ __forceinline__ const ushort* IMGc(const ushort* ws, int imgN, int h, int t, int i) {
  return ws + (((size_t)h * TB + t) * imgN + i) * 8192;
}

__global__ void __launch_bounds__(512, 2)
prepass(const float* __restrict__ q, const float* __restrict__ kk,
        const float* __restrict__ v, const float* __restrict__ dOg,
        ushort* __restrict__ ws, int imgN) {
  const int bid = blockIdx.x;          // 256 = h*16 + t
  const int h = bid >> 4, t = bid & 15;
  const int tid = threadIdx.x;
  const size_t off = (size_t)(t * BLK) * DMODEL + h * DKD;
  gwrow     (IMGp(ws, imgN, h, t, 0), kk + off, SCALEF, tid);
  gwrow     (IMGp(ws, imgN, h, t, 1), v  + off, 1.f,    tid);
  gwchunk<1>(IMGp(ws, imgN, h, t, 2), kk + off, SCALEF, tid);
  gwchunk<0>(IMGp(ws, imgN, h, t, 3), q  + off, SCALEF, tid);
  gwchunk<0>(IMGp(ws, imgN, h, t, 4), dOg + off, 1.f,   tid);
  if (imgN >= 7) {
    gwrow(IMGp(ws, imgN, h, t, 5), q   + off, 1.f, tid);
    gwrow(IMGp(ws, imgN, h, t, 6), dOg + off, 1.f, tid);
  }
}

// CACHED issue (images are multiply-reused across blocks -> keep in L2)
__device__ __forceinline__ void cp_issue(const ushort* src, int tid, ui4* r) {
  const ui4* s = reinterpret_cast<const ui4*>(src);
  r[0] = s[tid];
  r[1] = s[tid + 512];
}
__device__ __forceinline__ void lds_wr(ushort* dst, const ui4* r, int tid) {
  ui4* d = reinterpret_cast<ui4*>(dst);
  d[tid] = r[0];
  d[tid + 512] = r[1];
}

// ---- main kernel: 64 KB LDS -> 2 blocks/CU (R13 structure, cached loads) --
// grid 512: xcd(3b) | hpar(1b) | role(1b) | blk(4b)
// role 0: kR=0 vR=8192 kT16=16384 (single buf; 2 bars/iter; X-free dQ via K=16)
// role 1: kR=0 vR=8192 qT=16384 oT=24576; X (32 KB) overlays kR+vR; 6 bars/iter
__global__ void __launch_bounds__(512, 4)
bwd_roles(const float* __restrict__ q, const float* __restrict__ dOg,
          const ushort* __restrict__ ws, const int* __restrict__ mask, int imgN,
          float* __restrict__ dQ, float* __restrict__ dK, float* __restrict__ dV) {
  __shared__ ushort sm[32768];    // 64 KB
  const int tid = threadIdx.x;
  const int l = tid & 63, l15 = l & 15, lg = (l >> 4) & 3;
  const int w = tid >> 6, pw = w * 16;
  const int bid = blockIdx.x;
  const int xcd = bid & 7, idx = bid >> 3;
  const int h    = (xcd << 1) | (idx & 1);
  const int role = (idx >> 1) & 1;
  const int blk  = (idx >> 2) & 15;
  const f32x4 zz = {0.f, 0.f, 0.f, 0.f};

  if (role == 0) {
    // ================= dQ for (h, ib = blk), 2 barriers/iter ================
    ushort* kR = sm;
    ushort* vR = sm + 8192;
    ushort* kT = sm + 16384;
    unsigned bm = 0;
    for (int t = 0; t < TB; ++t)
      if (mask[blk * TB + t]) bm |= 1u << t;

    bf16x8 bq[2], bo[2];   // loop-invariant B-fragments (q, dO rows)
#pragma unroll
    for (int kb = 0; kb < 2; ++kb) {
      const size_t row = (size_t)(blk * BLK + pw + l15) * DMODEL + h * DKD + kb * 32 + lg * 8;
      bq[kb] = gfrag(q + row, 1.f);
      bo[kb] = gfrag(dOg + row, 1.f);
    }
    f32x4 accQT[4] = {zz, zz, zz, zz};   // dQ^T[d = df*16+lg*4+r][p = pw+l15]

    if (bm) {
      int j = __ffs(bm) - 1;
      unsigned rest = bm & (bm - 1);
      {
        ui4 t0[2], t1[2], t2[2];
        cp_issue(IMGc(ws, imgN, h, j, 0), tid, t0);
        cp_issue(IMGc(ws, imgN, h, j, 1), tid, t1);
        cp_issue(IMGc(ws, imgN, h, j, 2), tid, t2);
        lds_wr(kR, t0, tid);
        lds_wr(vR, t1, tid);
        lds_wr(kT, t2, tid);
      }
      __syncthreads();
      while (j >= 0) {
        const int jn = rest ? (__ffs(rest) - 1) : -1;
        rest = rest ? (rest & (rest - 1)) : 0u;
        ui4 pk0[2], pk1[2], pk2r[2];
        if (jn >= 0) {
          cp_issue(IMGc(ws, imgN, h, jn, 0), tid, pk0);
          cp_issue(IMGc(ws, imgN, h, jn, 1), tid, pk1);
          cp_issue(IMGc(ws, imgN, h, jn, 2), tid, pk2r);
        }

        // S^T = k.q^T, dA^T = v.dO^T ; lane: p = pw+l15, c = mf*16+lg*4+r
        f32x4 ST[8], dAT[8];
#pragma unroll
        for (int mf = 0; mf < 8; ++mf) { ST[mf] = zz; dAT[mf] = zz; }
#pragma unroll
        for (int kb = 0; kb < 2; ++kb) {
          const int ck = kb * 32 + lg * 8;
#pragma unroll
          for (int mf = 0; mf < 8; ++mf) {
            ST[mf]  = MFMA(frag64(kR, mf * 16 + l15, ck), bq[kb], ST[mf]);
            dAT[mf] = MFMA(frag64(vR, mf * 16 + l15, ck), bo[kb], dAT[mf]);
          }
        }
        // per-p softmax over 128 c
        float mx = -1e30f;
#pragma unroll
        for (int mf = 0; mf < 8; ++mf)
#pragma unroll
          for (int r = 0; r < 4; ++r) mx = fmaxf(mx, ST[mf][r]);
        mx = fmaxf(mx, __shfl_xor(mx, 16));
        mx = fmaxf(mx, __shfl_xor(mx, 32));
        float ss = 0.f;
#pragma unroll
        for (int mf = 0; mf < 8; ++mf)
#pragma unroll
          for (int r = 0; r < 4; ++r) { const float e = __expf(ST[mf][r] - mx); ST[mf][r] = e; ss += e; }
        ss += __shfl_xor(ss, 16);
        ss += __shfl_xor(ss, 32);
        const float inv = 1.f / (ss + 1e-12f);
        float rd = 0.f;
#pragma unroll
        for (int mf = 0; mf < 8; ++mf)
#pragma unroll
          for (int r = 0; r < 4; ++r) { const float pn = ST[mf][r] * inv; ST[mf][r] = pn; rd += pn * dAT[mf][r]; }
        rd += __shfl_xor(rd, 16);
        rd += __shfl_xor(rd, 32);

        f16x4 pb[8];   // dS as fp16 K=16 B-frags (k = lg*4+i)
#pragma unroll
        for (int mf = 0; mf < 8; ++mf)
#pragma unroll
          for (int r = 0; r < 4; ++r)
            pb[mf][r] = (_Float16)(ST[mf][r] * (dAT[mf][r] - rd));

        __syncthreads();                       // bar_a: kR/vR reads done
        if (jn >= 0) {
          lds_wr(kR, pk0, tid);                // safe: dQ phase touches only kT
          lds_wr(vR, pk1, tid);
        }
        // dQ^T[d][p] += sum_c kT[d][c] * dS[p][c]  (32x mfma 16x16x16 f16)
#pragma unroll
        for (int df = 0; df < 4; ++df)
#pragma unroll
          for (int mf = 0; mf < 8; ++mf)
            accQT[df] = MFMA16(fragK16(kT, df * 16 + l15, mf * 4 + lg), pb[mf], accQT[df]);
        __syncthreads();                       // bar_b: kT reads done; kR'/vR' visible
        if (jn >= 0) lds_wr(kT, pk2r, tid);    // kT' fenced by next bar_a
        j = jn;
      }
    }
    // epilogue: lane holds dQ^T[df*16+lg*4+r][pw+l15]
#pragma unroll
    for (int df = 0; df < 4; ++df) {
      f32x4 wv;
      wv[0] = accQT[df][0]; wv[1] = accQT[df][1];
      wv[2] = accQT[df][2]; wv[3] = accQT[df][3];
      __builtin_nontemporal_store(wv, reinterpret_cast<f32x4*>(
          dQ + (size_t)(blk * BLK + pw + l15) * DMODEL + h * DKD + df * 16 + lg * 4));
    }

  } else {
    // ================= dK, dV for (h, jb = blk), 6 barriers/iter ============
    ushort* kR = sm;
    ushort* vR = sm + 8192;
    ushort* qT = sm + 16384;
    ushort* oT = sm + 24576;
    ushort* X  = sm;           // 32 KB overlay of kR+vR
    const int jb = blk;
    unsigned bm = 0;
    for (int t = 0; t < TB; ++t)
      if (mask[t * TB + jb]) bm |= 1u << t;

    f32x4 accK[4] = {zz, zz, zz, zz};
    f32x4 accV[4] = {zz, zz, zz, zz};

    if (bm) {
      const bool hasR = (imgN >= 7);
      int i = __ffs(bm) - 1;
      unsigned rest = bm & (bm - 1);
      {
        ui4 t0[2], t1[2], t2[2], t3[2];
        cp_issue(IMGc(ws, imgN, h, jb, 0), tid, t0);
        cp_issue(IMGc(ws, imgN, h, jb, 1), tid, t1);
        cp_issue(IMGc(ws, imgN, h, i, 3), tid, t2);
        cp_issue(IMGc(ws, imgN, h, i, 4), tid, t3);
        lds_wr(kR, t0, tid);
        lds_wr(vR, t1, tid);
        lds_wr(qT, t2, tid);
        lds_wr(oT, t3, tid);
      }
      __syncthreads();

      while (i >= 0) {
        const int in = rest ? (__ffs(rest) - 1) : -1;
        rest = rest ? (rest & (rest - 1)) : 0u;

        // A-fragments for current i (L2-hot images / fp32 fallback)
        bf16x8 aq[2], ao[2];
        if (hasR) {
#pragma unroll
          for (int kb = 0; kb < 2; ++kb) {
            aq[kb] = frag64(IMGc(ws, imgN, h, i, 5), pw + l15, kb * 32 + lg * 8);
            ao[kb] = frag64(IMGc(ws, imgN, h, i, 6), pw + l15, kb * 32 + lg * 8);
          }
        } else {
#pragma unroll
          for (int kb = 0; kb < 2; ++kb) {
            const size_t row = (size_t)(i * BLK + pw + l15) * DMODEL + h * DKD + kb * 32 + lg * 8;
            aq[kb] = gfrag(q + row, 1.f);
            ao[kb] = gfrag(dOg + row, 1.f);
          }
        }

        // S = q.k^T, dA = dO.v^T ; lane: p = pw+lg*4+r, c = nf*16+l15
        f32x4 S[8], dA[8];
#pragma unroll
        for (int nf = 0; nf < 8; ++nf) { S[nf] = zz; dA[nf] = zz; }
#pragma unroll
        for (int kb = 0; kb < 2; ++kb) {
          const int ck = kb * 32 + lg * 8;
#pragma unroll
          for (int nf = 0; nf < 8; ++nf) {
            S[nf]  = MFMA(aq[kb], frag64(kR, nf * 16 + l15, ck), S[nf]);
            dA[nf] = MFMA(ao[kb], frag64(vR, nf * 16 + l15, ck), dA[nf]);
          }
        }
        // softmax over c per row; dS = Pn*(dA - rowdot)
#pragma unroll
        for (int r = 0; r < 4; ++r) {
          float mx = -1e30f;
#pragma unroll
          for (int nf = 0; nf < 8; ++nf) mx = fmaxf(mx, S[nf][r]);
          mx = fmaxf(mx, __shfl_xor(mx, 1));
          mx = fmaxf(mx, __shfl_xor(mx, 2));
          mx = fmaxf(mx, __shfl_xor(mx, 4));
          mx = fmaxf(mx, __shfl_xor(mx, 8));
          float ss = 0.f;
#pragma unroll
          for (int nf = 0; nf < 8; ++nf) { const float e = __expf(S[nf][r] - mx); S[nf][r] = e; ss += e; }
          ss += __shfl_xor(ss, 1); ss += __shfl_xor(ss, 2);
          ss += __shfl_xor(ss, 4); ss += __shfl_xor(ss, 8);
          const float inv = 1.f / (ss + 1e-12f);
          float rd = 0.f;
#pragma unroll
          for (int nf = 0; nf < 8; ++nf) { const float pn = S[nf][r] * inv; S[nf][r] = pn; rd += pn * dA[nf][r]; }
          rd += __shfl_xor(rd, 1); rd += __shfl_xor(rd, 2);
          rd += __shfl_xor(rd, 4); rd += __shfl_xor(rd, 8);
#pragma unroll
          for (int nf = 0; nf < 8; ++nf) dA[nf][r] = S[nf][r] * (dA[nf][r] - rd);
        }
        __syncthreads();                       // bar_a: kR/vR reads done (X writable)

        // write Pn^T [c][p] into X
#pragma unroll
        for (int nf = 0; nf < 8; ++nf) {
          const int c = nf * 16 + l15;
          const int off = (c * 128 + pw + 4 * lg) ^ ((c & 7) << 3);
          const ushort2 lo = pk2(S[nf][0], S[nf][1]);
          const ushort2 hi = pk2(S[nf][2], S[nf][3]);
          ushort4 u; u.x = lo.x; u.y = lo.y; u.z = hi.x; u.w = hi.y;
          *reinterpret_cast<ushort4*>(X + off) = u;
        }
        __syncthreads();                       // bar_b: PnT visible

        // dV += Pn^T @ dO  (B from depth-8 oT, b128)
#pragma unroll
        for (int kp = 0; kp < 4; ++kp) {
          const int pp = kp * 32 + lg * 8;
          const bf16x8 a = frag128(X, pw + l15, pp);
#pragma unroll
          for (int nfd = 0; nfd < 4; ++nfd)
            accV[nfd] = MFMA(a, fragT8(oT, nfd * 16 + l15, pp), accV[nfd]);
        }
        __syncthreads();                       // bar_c: PnT reads done

        // issue restage loads (covered by dST write + bar_d + dK phase)
        ui4 pk0[2], pk1[2], pq[2], po[2];
        if (in >= 0) {
          cp_issue(IMGc(ws, imgN, h, jb, 0), tid, pk0);
          cp_issue(IMGc(ws, imgN, h, jb, 1), tid, pk1);
          cp_issue(IMGc(ws, imgN, h, in, 3), tid, pq);
          cp_issue(IMGc(ws, imgN, h, in, 4), tid, po);
        }

        // write dS^T [c][p] into X
#pragma unroll
        for (int nf = 0; nf < 8; ++nf) {
          const int c = nf * 16 + l15;
          const int off = (c * 128 + pw + 4 * lg) ^ ((c & 7) << 3);
          const ushort2 lo = pk2(dA[nf][0], dA[nf][1]);
          const ushort2 hi = pk2(dA[nf][2], dA[nf][3]);
          ushort4 u; u.x = lo.x; u.y = lo.y; u.z = hi.x; u.w = hi.y;
          *reinterpret_cast<ushort4*>(X + off) = u;
        }
        __syncthreads();                       // bar_d: dST visible

        // dK += dS^T @ q  (B from depth-8 qT, b128; q pre-scaled)
#pragma unroll
        for (int kp = 0; kp < 4; ++kp) {
          const int pp = kp * 32 + lg * 8;
          const bf16x8 a = frag128(X, pw + l15, pp);
#pragma unroll
          for (int nfd = 0; nfd < 4; ++nfd)
            accK[nfd] = MFMA(a, fragT8(qT, nfd * 16 + l15, pp), accK[nfd]);
        }
        __syncthreads();                       // bar_e: X free; qT/oT reads done

        if (in >= 0) {
          lds_wr(kR, pk0, tid);
          lds_wr(vR, pk1, tid);
          lds_wr(qT, pq, tid);
          lds_wr(oT, po, tid);
          __syncthreads();                     // bar_f: staged tiles visible
        }
        i = in;
      }
    }
#pragma unroll
    for (int nfd = 0; nfd < 4; ++nfd)
#pragma unroll
      for (int r = 0; r < 4; ++r) {
        const size_t rowo = (size_t)(jb * BLK + pw + lg * 4 + r) * DMODEL + h * DKD + nfd * 16 + l15;
        __builtin_nontemporal_store(accK[nfd][r], &dK[rowo]);
        __builtin_nontemporal_store(accV[nfd][r], &dV[rowo]);
      }
  }
}

extern "C" void kernel_launch(void* const* d_in, const int* in_sizes, int n_in,
                              void* d_out, int out_size, void* d_ws, size_t ws_size,
                              hipStream_t stream) {
  const float* q  = (const float*)d_in[0];
  const float* k  = (const float*)d_in[1];
  const float* v  = (const float*)d_in[2];
  const float* dO = (const float*)d_in[3];
  const int* mask = (const int*)d_in[4];
  float* out = (float*)d_out;
  float* dQ = out;
  float* dK = out + (size_t)2048 * DMODEL;
  float* dV = out + (size_t)2 * 2048 * DMODEL;
  ushort* ws = (ushort*)d_ws;

  const size_t need7 = (size_t)NHEAD * TB * 7 * 16384;  // 28.7 MB
  const int imgN = (ws_size >= need7) ? 7 : 5;

  prepass<<<NHEAD * TB, 512, 0, stream>>>(q, k, v, dO, ws, imgN);
  bwd_roles<<<2 * NHEAD * TB, 512, 0, stream>>>(q, dO, ws, mask, imgN, dQ, dK, dV);
}

// Round 16
// 102.826 us; speedup vs baseline: 1.9732x; 1.9732x over previous
//
#include <hip/hip_runtime.h>
#include <hip/hip_bf16.h>

#define DMODEL 1024
#define NHEAD  16
#define DKD    64
#define BLK    128
#define TB     16
#define SCALEF 0.125f   // TAU / sqrt(DK)

typedef __attribute__((ext_vector_type(8))) short bf16x8;
typedef __attribute__((ext_vector_type(4))) _Float16 f16x4;
typedef __attribute__((ext_vector_type(4))) float f32x4;

#define MFMA(A, B, C)   __builtin_amdgcn_mfma_f32_16x16x32_bf16(A, B, C, 0, 0, 0)
#define MFMA16(A, B, C) __builtin_amdgcn_mfma_f32_16x16x16f16(A, B, C, 0, 0, 0)

union U8 { bf16x8 v; ushort u[8]; ushort2 u2[4]; ushort4 u4[2]; };

__device__ __forceinline__ ushort2 pk2(float a, float b) {
  union { __hip_bfloat162 h; ushort2 u; } c;
  c.h = __float22bfloat162_rn(make_float2(a, b));
  return c.u;
}
__device__ __forceinline__ ushort4 pkh4(float a, float b, float c, float d) {
  union { f16x4 h; ushort4 u; } z;
  z.h[0] = (_Float16)a; z.h[1] = (_Float16)b;
  z.h[2] = (_Float16)c; z.h[3] = (_Float16)d;
  return z.u;
}

// ---- tile-image readers (R13/R15-proven) ----------------------------------
// row tile [128][64] bf16, XOR-swizzled by ((r&7)<<3)
__device__ __forceinline__ bf16x8 frag64(const ushort* T, int r, int c) {
  return *reinterpret_cast<const bf16x8*>(T + ((r * 64 + c) ^ ((r & 7) << 3)));
}
// [128][128] bf16 tile, same swizzle
__device__ __forceinline__ bf16x8 frag128(const ushort* T, int r, int c) {
  return *reinterpret_cast<const bf16x8*>(T + ((r * 128 + c) ^ ((r & 7) << 3)));
}
// depth-8 chunked transposed tile [64 d][128 r]: elem (d,r) at
// (r>>3)*512 + d*8 + (r&7)
__device__ __forceinline__ bf16x8 fragT8(const ushort* T, int d, int r0) {
  return *reinterpret_cast<const bf16x8*>(T + (r0 >> 3) * 512 + d * 8);  // r0%8==0
}
// K=16 A-frag from fp16 depth-8 tile: elems (d, 4g..4g+3) -> one b64 read
__device__ __forceinline__ f16x4 fragK16(const ushort* T, int d, int g) {
  union { ushort4 u; f16x4 h; } z;
  z.u = *reinterpret_cast<const ushort4*>(T + (g >> 1) * 512 + d * 8 + 4 * (g & 1));
  return z.h;
}
// global fp32 row-major -> bf16 register fragment
__device__ __forceinline__ bf16x8 gfrag(const float* __restrict__ g, float sc) {
  const float4 fa = *reinterpret_cast<const float4*>(g);
  const float4 fb = *reinterpret_cast<const float4*>(g + 4);
  U8 x;
  x.u2[0] = pk2(fa.x * sc, fa.y * sc);
  x.u2[1] = pk2(fa.z * sc, fa.w * sc);
  x.u2[2] = pk2(fb.x * sc, fb.y * sc);
  x.u2[3] = pk2(fb.z * sc, fb.w * sc);
  return x.v;
}

// ---- prepass image writers (512 threads) ----------------------------------
__device__ __forceinline__ void gwrow(ushort* T, const float* __restrict__ g,
                                      float sc, int tid) {
#pragma unroll
  for (int it = 0; it < 4; ++it) {
    const int idx = tid + 512 * it;
    const int r = idx >> 4, d4 = idx & 15;
    const float4 f = *reinterpret_cast<const float4*>(g + r * DMODEL + 4 * d4);
    const ushort2 lo = pk2(f.x * sc, f.y * sc);
    const ushort2 hi = pk2(f.z * sc, f.w * sc);
    ushort4 u; u.x = lo.x; u.y = lo.y; u.z = hi.x; u.w = hi.y;
    *reinterpret_cast<ushort4*>(T + ((r * 64 + 4 * d4) ^ ((r & 7) << 3))) = u;
  }
}
// shfl butterfly transpose -> depth-8 chunked tile; HALF=1 => fp16 payload
template <int HALF>
__device__ __forceinline__ void gwchunk(ushort* T, const float* __restrict__ g,
                                        float sc, int tid) {
  const int a = (tid >> 4) & 3;
#pragma unroll
  for (int it = 0; it < 4; ++it) {
    const int idx = tid + 512 * it;
    const int r = idx >> 4, d4 = idx & 15;
    const float4 f = *reinterpret_cast<const float4*>(g + r * DMODEL + 4 * d4);
    const float w0 = f.x * sc, w1 = f.y * sc, w2 = f.z * sc, w3 = f.w * sc;
    const float s0 = __shfl_xor(w1, 16), s1 = __shfl_xor(w0, 16);
    const float s2 = __shfl_xor(w3, 16), s3 = __shfl_xor(w2, 16);
    const float u0 = (a & 1) ? s0 : w0;
    const float u1 = (a & 1) ? w1 : s1;
    const float u2 = (a & 1) ? s2 : w2;
    const float u3 = (a & 1) ? w3 : s3;
    const float t0 = __shfl_xor(u2, 32), t1 = __shfl_xor(u3, 32);
    const float t2 = __shfl_xor(u0, 32), t3 = __shfl_xor(u1, 32);
    const float z0 = (a & 2) ? t0 : u0;
    const float z1 = (a & 2) ? t1 : u1;
    const float z2 = (a & 2) ? u2 : t2;
    const float z3 = (a & 2) ? u3 : t3;
    const int d = 4 * d4 + a, R0 = r - a;   // lane holds rows R0..R0+3 of col d
    ushort4 o;
    if constexpr (HALF) {
      o = pkh4(z0, z1, z2, z3);
    } else {
      const ushort2 lo = pk2(z0, z1);
      const ushort2 hi = pk2(z2, z3);
      o.x = lo.x; o.y = lo.y; o.z = hi.x; o.w = hi.y;
    }
    *reinterpret_cast<ushort4*>(T + (R0 >> 3) * 512 + d * 8 + (R0 & 7)) = o;
  }
}

// images per (h,t): 0 KR(bf16,k*s) 1 VR(bf16,v) 2 KT16(fp16,k*s,d8)
//                   3 QT(bf16,q*s,d8) 4 OT(bf16,dO,d8) 5 QR(bf16,q) 6 OR(bf16,dO)
__device__ __forceinline__ ushort* IMGp(ushort* ws, int imgN, int h, int t, int i) {
  return ws + (((size_t)h * TB + t) * imgN + i) * 8192;
}
__device__ __forceinline__ const ushort* IMGc(const ushort* ws, int imgN, int h, int t, int i) {
  return ws + (((size_t)h * TB + t) * imgN + i) * 8192;
}

__global__ void __launch_bounds__(512, 2)
prepass(const float* __restrict__ q, const float* __restrict__ kk,
        const float* __restrict__ v, const float* __restrict__ dOg,
        ushort* __restrict__ ws, int imgN) {
  const int bid = blockIdx.x;          // 256 = h*16 + t
  const int h = bid >> 4, t = bid & 15;
  const int tid = threadIdx.x;
  const size_t off = (size_t)(t * BLK) * DMODEL + h * DKD;
  gwrow     (IMGp(ws, imgN, h, t, 0), kk + off, SCALEF, tid);
  gwrow     (IMGp(ws, imgN, h, t, 1), v  + off, 1.f,    tid);
  gwchunk<1>(IMGp(ws, imgN, h, t, 2), kk + off, SCALEF, tid);
  gwchunk<0>(IMGp(ws, imgN, h, t, 3), q  + off, SCALEF, tid);
  gwchunk<0>(IMGp(ws, imgN, h, t, 4), dOg + off, 1.f,   tid);
  if (imgN >= 7) {
    gwrow(IMGp(ws, imgN, h, t, 5), q   + off, 1.f, tid);
    gwrow(IMGp(ws, imgN, h, t, 6), dOg + off, 1.f, tid);
  }
}

// ---- 16 KB image -> LDS via global_load_lds (no VGPR round-trip) ----------
// dest: wave-uniform LDS base + lane*16 (HW); src: per-lane matching address.
typedef __attribute__((address_space(1))) const unsigned int g_u32;
typedef __attribute__((address_space(3))) unsigned int l_u32;
__device__ __forceinline__ void img_to_lds(ushort* dst, const ushort* src, int tid) {
  const int w = tid >> 6, lane = tid & 63;
  const char* g = reinterpret_cast<const char*>(src) + w * 1024 + lane * 16;
  char* l = reinterpret_cast<char*>(dst) + w * 1024;
  __builtin_amdgcn_global_load_lds((g_u32*)(g),        (l_u32*)(l),        16, 0, 0);
  __builtin_amdgcn_global_load_lds((g_u32*)(g + 8192), (l_u32*)(l + 8192), 16, 0, 0);
}

// ---- main kernel: 64 KB LDS, launch_bounds(512,2) -> true 2 blocks/CU -----
// grid 512: xcd(3b) | hpar(1b) | role(1b) | blk(4b)
// role 0: kR=0 vR=8192 kT16=16384 (48 KB; 2 bars/iter; X-free dQ via K=16)
// role 1: kR=0 vR=8192 qT=16384 oT=24576; X (32 KB) overlays kR+vR; 6 bars/iter
__global__ void __launch_bounds__(512, 2)
bwd_roles(const float* __restrict__ q, const float* __restrict__ dOg,
          const ushort* __restrict__ ws, const int* __restrict__ mask, int imgN,
          float* __restrict__ dQ, float* __restrict__ dK, float* __restrict__ dV) {
  __shared__ ushort sm[32768];    // 64 KB
  const int tid = threadIdx.x;
  const int l = tid & 63, l15 = l & 15, lg = (l >> 4) & 3;
  const int w = tid >> 6, pw = w * 16;
  const int bid = blockIdx.x;
  const int xcd = bid & 7, idx = bid >> 3;
  const int h    = (xcd << 1) | (idx & 1);
  const int role = (idx >> 1) & 1;
  const int blk  = (idx >> 2) & 15;
  const f32x4 zz = {0.f, 0.f, 0.f, 0.f};

  if (role == 0) {
    // ================= dQ for (h, ib = blk), 2 barriers/iter ================
    ushort* kR = sm;
    ushort* vR = sm + 8192;
    ushort* kT = sm + 16384;
    unsigned bm = 0;
    for (int t = 0; t < TB; ++t)
      if (mask[blk * TB + t]) bm |= 1u << t;

    bf16x8 bq[2], bo[2];   // loop-invariant B-fragments (q, dO rows)
#pragma unroll
    for (int kb = 0; kb < 2; ++kb) {
      const size_t row = (size_t)(blk * BLK + pw + l15) * DMODEL + h * DKD + kb * 32 + lg * 8;
      bq[kb] = gfrag(q + row, 1.f);
      bo[kb] = gfrag(dOg + row, 1.f);
    }
    f32x4 accQT[4] = {zz, zz, zz, zz};   // dQ^T[d = df*16+lg*4+r][p = pw+l15]

    if (bm) {
      int j = __ffs(bm) - 1;
      unsigned rest = bm & (bm - 1);
      img_to_lds(kR, IMGc(ws, imgN, h, j, 0), tid);
      img_to_lds(vR, IMGc(ws, imgN, h, j, 1), tid);
      img_to_lds(kT, IMGc(ws, imgN, h, j, 2), tid);
      __syncthreads();
      while (j >= 0) {
        const int jn = rest ? (__ffs(rest) - 1) : -1;
        rest = rest ? (rest & (rest - 1)) : 0u;

        // S^T = k.q^T, dA^T = v.dO^T ; lane: p = pw+l15, c = mf*16+lg*4+r
        f32x4 ST[8], dAT[8];
#pragma unroll
        for (int mf = 0; mf < 8; ++mf) { ST[mf] = zz; dAT[mf] = zz; }
#pragma unroll
        for (int kb = 0; kb < 2; ++kb) {
          const int ck = kb * 32 + lg * 8;
#pragma unroll
          for (int mf = 0; mf < 8; ++mf) {
            ST[mf]  = MFMA(frag64(kR, mf * 16 + l15, ck), bq[kb], ST[mf]);
            dAT[mf] = MFMA(frag64(vR, mf * 16 + l15, ck), bo[kb], dAT[mf]);
          }
        }
        // per-p softmax over 128 c
        float mx = -1e30f;
#pragma unroll
        for (int mf = 0; mf < 8; ++mf)
#pragma unroll
          for (int r = 0; r < 4; ++r) mx = fmaxf(mx, ST[mf][r]);
        mx = fmaxf(mx, __shfl_xor(mx, 16));
        mx = fmaxf(mx, __shfl_xor(mx, 32));
        float ss = 0.f;
#pragma unroll
        for (int mf = 0; mf < 8; ++mf)
#pragma unroll
          for (int r = 0; r < 4; ++r) { const float e = __expf(ST[mf][r] - mx); ST[mf][r] = e; ss += e; }
        ss += __shfl_xor(ss, 16);
        ss += __shfl_xor(ss, 32);
        const float inv = 1.f / (ss + 1e-12f);
        float rd = 0.f;
#pragma unroll
        for (int mf = 0; mf < 8; ++mf)
#pragma unroll
          for (int r = 0; r < 4; ++r) { const float pn = ST[mf][r] * inv; ST[mf][r] = pn; rd += pn * dAT[mf][r]; }
        rd += __shfl_xor(rd, 16);
        rd += __shfl_xor(rd, 32);

        f16x4 pb[8];   // dS as fp16 K=16 B-frags (k = lg*4+i)
#pragma unroll
        for (int mf = 0; mf < 8; ++mf)
#pragma unroll
          for (int r = 0; r < 4; ++r)
            pb[mf][r] = (_Float16)(ST[mf][r] * (dAT[mf][r] - rd));

        // dQ^T[d][p] += sum_c kT[d][c] * dS[p][c]  (32x mfma 16x16x16 f16)
#pragma unroll
        for (int df = 0; df < 4; ++df)
#pragma unroll
          for (int mf = 0; mf < 8; ++mf)
            accQT[df] = MFMA16(fragK16(kT, df * 16 + l15, mf * 4 + lg), pb[mf], accQT[df]);

        __syncthreads();                       // bar_a: all LDS reads done
        if (jn >= 0) {
          img_to_lds(kR, IMGc(ws, imgN, h, jn, 0), tid);
          img_to_lds(vR, IMGc(ws, imgN, h, jn, 1), tid);
          img_to_lds(kT, IMGc(ws, imgN, h, jn, 2), tid);
          __syncthreads();                     // bar_b: staged tiles visible
        }
        j = jn;
      }
    }
    // epilogue: lane holds dQ^T[df*16+lg*4+r][pw+l15]
#pragma unroll
    for (int df = 0; df < 4; ++df) {
      f32x4 wv;
      wv[0] = accQT[df][0]; wv[1] = accQT[df][1];
      wv[2] = accQT[df][2]; wv[3] = accQT[df][3];
      __builtin_nontemporal_store(wv, reinterpret_cast<f32x4*>(
          dQ + (size_t)(blk * BLK + pw + l15) * DMODEL + h * DKD + df * 16 + lg * 4));
    }

  } else {
    // ================= dK, dV for (h, jb = blk), 6 barriers/iter ============
    ushort* kR = sm;
    ushort* vR = sm + 8192;
    ushort* qT = sm + 16384;
    ushort* oT = sm + 24576;
    ushort* X  = sm;           // 32 KB overlay of kR+vR
    const int jb = blk;
    unsigned bm = 0;
    for (int t = 0; t < TB; ++t)
      if (mask[t * TB + jb]) bm |= 1u << t;

    f32x4 accK[4] = {zz, zz, zz, zz};
    f32x4 accV[4] = {zz, zz, zz, zz};

    if (bm) {
      const bool hasR = (imgN >= 7);
      int i = __ffs(bm) - 1;
      unsigned rest = bm & (bm - 1);
      img_to_lds(kR, IMGc(ws, imgN, h, jb, 0), tid);
      img_to_lds(vR, IMGc(ws, imgN, h, jb, 1), tid);
      img_to_lds(qT, IMGc(ws, imgN, h, i, 3), tid);
      img_to_lds(oT, IMGc(ws, imgN, h, i, 4), tid);
      __syncthreads();

      while (i >= 0) {
        const int in = rest ? (__ffs(rest) - 1) : -1;
        rest = rest ? (rest & (rest - 1)) : 0u;

        // S = q.k^T, dA = dO.v^T ; lane: p = pw+lg*4+r, c = nf*16+l15
        // A-fragments loaded just-in-time (L2-hot images / fp32 fallback)
        f32x4 S[8], dA[8];
#pragma unroll
        for (int nf = 0; nf < 8; ++nf) { S[nf] = zz; dA[nf] = zz; }
#pragma unroll
        for (int kb = 0; kb < 2; ++kb) {
          const int ck = kb * 32 + lg * 8;
          bf16x8 aq, ao;
          if (hasR) {
            aq = frag64(IMGc(ws, imgN, h, i, 5), pw + l15, ck);
            ao = frag64(IMGc(ws, imgN, h, i, 6), pw + l15, ck);
          } else {
            const size_t row = (size_t)(i * BLK + pw + l15) * DMODEL + h * DKD + ck;
            aq = gfrag(q + row, 1.f);
            ao = gfrag(dOg + row, 1.f);
          }
#pragma unroll
          for (int nf = 0; nf < 8; ++nf) {
            S[nf]  = MFMA(aq, frag64(kR, nf * 16 + l15, ck), S[nf]);
            dA[nf] = MFMA(ao, frag64(vR, nf * 16 + l15, ck), dA[nf]);
          }
        }
        // softmax over c per row; dS = Pn*(dA - rowdot)
#pragma unroll
        for (int r = 0; r < 4; ++r) {
          float mx = -1e30f;
#pragma unroll
          for (int nf = 0; nf < 8; ++nf) mx = fmaxf(mx, S[nf][r]);
          mx = fmaxf(mx, __shfl_xor(mx, 1));
          mx = fmaxf(mx, __shfl_xor(mx, 2));
          mx = fmaxf(mx, __shfl_xor(mx, 4));
          mx = fmaxf(mx, __shfl_xor(mx, 8));
          float ss = 0.f;
#pragma unroll
          for (int nf = 0; nf < 8; ++nf) { const float e = __expf(S[nf][r] - mx); S[nf][r] = e; ss += e; }
          ss += __shfl_xor(ss, 1); ss += __shfl_xor(ss, 2);
          ss += __shfl_xor(ss, 4); ss += __shfl_xor(ss, 8);
          const float inv = 1.f / (ss + 1e-12f);
          float rd = 0.f;
#pragma unroll
          for (int nf = 0; nf < 8; ++nf) { const float pn = S[nf][r] * inv; S[nf][r] = pn; rd += pn * dA[nf][r]; }
          rd += __shfl_xor(rd, 1); rd += __shfl_xor(rd, 2);
          rd += __shfl_xor(rd, 4); rd += __shfl_xor(rd, 8);
#pragma unroll
          for (int nf = 0; nf < 8; ++nf) dA[nf][r] = S[nf][r] * (dA[nf][r] - rd);
        }
        __syncthreads();                       // bar_a: kR/vR reads done (X writable)

        // write Pn^T [c][p] into X
#pragma unroll
        for (int nf = 0; nf < 8; ++nf) {
          const int c = nf * 16 + l15;
          const int off = (c * 128 + pw + 4 * lg) ^ ((c & 7) << 3);
          const ushort2 lo = pk2(S[nf][0], S[nf][1]);
          const ushort2 hi = pk2(S[nf][2], S[nf][3]);
          ushort4 u; u.x = lo.x; u.y = lo.y; u.z = hi.x; u.w = hi.y;
          *reinterpret_cast<ushort4*>(X + off) = u;
        }
        __syncthreads();                       // bar_b: PnT visible

        // dV += Pn^T @ dO  (B from depth-8 oT, b128)
#pragma unroll
        for (int kp = 0; kp < 4; ++kp) {
          const int pp = kp * 32 + lg * 8;
          const bf16x8 a = frag128(X, pw + l15, pp);
#pragma unroll
          for (int nfd = 0; nfd < 4; ++nfd)
            accV[nfd] = MFMA(a, fragT8(oT, nfd * 16 + l15, pp), accV[nfd]);
        }
        __syncthreads();                       // bar_c: PnT reads done

        // write dS^T [c][p] into X
#pragma unroll
        for (int nf = 0; nf < 8; ++nf) {
          const int c = nf * 16 + l15;
          const int off = (c * 128 + pw + 4 * lg) ^ ((c & 7) << 3);
          const ushort2 lo = pk2(dA[nf][0], dA[nf][1]);
          const ushort2 hi = pk2(dA[nf][2], dA[nf][3]);
          ushort4 u; u.x = lo.x; u.y = lo.y; u.z = hi.x; u.w = hi.y;
          *reinterpret_cast<ushort4*>(X + off) = u;
        }
        __syncthreads();                       // bar_d: dST visible

        // dK += dS^T @ q  (B from depth-8 qT, b128; q pre-scaled)
#pragma unroll
        for (int kp = 0; kp < 4; ++kp) {
          const int pp = kp * 32 + lg * 8;
          const bf16x8 a = frag128(X, pw + l15, pp);
#pragma unroll
          for (int nfd = 0; nfd < 4; ++nfd)
            accK[nfd] = MFMA(a, fragT8(qT, nfd * 16 + l15, pp), accK[nfd]);
        }
        __syncthreads();                       // bar_e: X free; qT/oT reads done

        if (in >= 0) {
          img_to_lds(kR, IMGc(ws, imgN, h, jb, 0), tid);
          img_to_lds(vR, IMGc(ws, imgN, h, jb, 1), tid);
          img_to_lds(qT, IMGc(ws, imgN, h, in, 3), tid);
          img_to_lds(oT, IMGc(ws, imgN, h, in, 4), tid);
          __syncthreads();                     // bar_f: staged tiles visible
        }
        i = in;
      }
    }
#pragma unroll
    for (int nfd = 0; nfd < 4; ++nfd)
#pragma unroll
      for (int r = 0; r < 4; ++r) {
        const size_t rowo = (size_t)(jb * BLK + pw + lg * 4 + r) * DMODEL + h * DKD + nfd * 16 + l15;
        __builtin_nontemporal_store(accK[nfd][r], &dK[rowo]);
        __builtin_nontemporal_store(accV[nfd][r], &dV[rowo]);
      }
  }
}

extern "C" void kernel_launch(void* const* d_in, const int* in_sizes, int n_in,
                              void* d_out, int out_size, void* d_ws, size_t ws_size,
                              hipStream_t stream) {
  const float* q  = (const float*)d_in[0];
  const float* k  = (const float*)d_in[1];
  const float* v  = (const float*)d_in[2];
  const float* dO = (const float*)d_in[3];
  const int* mask = (const int*)d_in[4];
  float* out = (float*)d_out;
  float* dQ = out;
  float* dK = out + (size_t)2048 * DMODEL;
  float* dV = out + (size_t)2 * 2048 * DMODEL;
  ushort* ws = (ushort*)d_ws;

  const size_t need7 = (size_t)NHEAD * TB * 7 * 16384;  // 28.7 MB
  const int imgN = (ws_size >= need7) ? 7 : 5;

  prepass<<<NHEAD * TB, 512, 0, stream>>>(q, k, v, dO, ws, imgN);
  bwd_roles<<<2 * NHEAD * TB, 512, 0, stream>>>(q, dO, ws, mask, imgN, dQ, dK, dV);
}